// Round 1
// baseline (1979.231 us; speedup 1.0000x reference)
//
#include <hip/hip_runtime.h>

// CLAGCN forward on MI355X.
// Structure per launch:
//   1. CSR build for both graphs (count -> scan(+dinv) -> fill with norms)
//   2. Layer 1: 4 GEMMs (128->64 into column halves), 2 aggs (F=128), stats, gate, combine
//   3. 2 middle layers: 1 GEMM (128->128) shared by both branches, 2 aggs, stats, gate, combine
//   4. Final: GEMM (128->40), 2 aggs (F=40) straight into d_out, gate, mix
// Workspace ~91 MB: three N x 128 fp32 buffers (P,Q,R) + 2 CSRs + small stats area.

#define DFEAT 128

// ---------------- CSR build ----------------
__global__ void count_kernel(const int* __restrict__ dst, int* __restrict__ counts, int E) {
    int i = blockIdx.x * blockDim.x + threadIdx.x;
    if (i < E) atomicAdd(&counts[dst[i]], 1);
}

__global__ __launch_bounds__(1024) void scan_kernel(const int* __restrict__ counts,
                                                    int* __restrict__ row_ptr,
                                                    float* __restrict__ dinv, int n) {
    const int T = 1024;
    int t = threadIdx.x;
    int C = (n + T - 1) / T;
    int lo = t * C;
    int hi = min(lo + C, n);
    int sum = 0;
    for (int i = lo; i < hi; ++i) sum += counts[i];
    __shared__ int buf[T];
    buf[t] = sum;
    __syncthreads();
    for (int off = 1; off < T; off <<= 1) {
        int x = (t >= off) ? buf[t - off] : 0;
        __syncthreads();
        buf[t] += x;
        __syncthreads();
    }
    int run = buf[t] - sum;  // exclusive prefix of this thread's chunk
    for (int i = lo; i < hi; ++i) {
        int v = counts[i];
        row_ptr[i] = run;
        dinv[i] = rsqrtf((float)(v + 1));  // +1 self-loop; deg>=1 always
        run += v;
    }
    if (t == T - 1) row_ptr[n] = run;
}

__global__ void fill_kernel(const int* __restrict__ src, const int* __restrict__ dst,
                            const int* __restrict__ row_ptr, int* __restrict__ fill,
                            int* __restrict__ csr_src, float* __restrict__ csr_norm,
                            const float* __restrict__ dinv, int E) {
    int i = blockIdx.x * blockDim.x + threadIdx.x;
    if (i >= E) return;
    int d = dst[i];
    int s = src[i];
    int pos = row_ptr[d] + atomicAdd(&fill[d], 1);
    csr_src[pos] = s;
    csr_norm[pos] = dinv[s] * dinv[d];
}

// ---------------- aggregation (gather over CSR) ----------------
// One GROUP of lanes per node; lane handles float4 column chunk. Self-loop folded in.
template <int FV, int GROUP>
__global__ void agg_kernel(const float* __restrict__ h, const int* __restrict__ row_ptr,
                           const int* __restrict__ csr_src, const float* __restrict__ csr_norm,
                           const float* __restrict__ dinv, const float* __restrict__ bias,
                           float* __restrict__ out, int n) {
    int gid = (blockIdx.x * blockDim.x + threadIdx.x) / GROUP;
    int lane = threadIdx.x & (GROUP - 1);
    if (gid >= n) return;
    int node = gid;
    bool act = (lane < FV);
    float dn = dinv[node];
    float4 acc = make_float4(0.f, 0.f, 0.f, 0.f);
    if (act) {
        float4 hv = ((const float4*)(h + (size_t)node * FV * 4))[lane];
        float w = dn * dn;  // self-loop norm
        acc.x = hv.x * w; acc.y = hv.y * w; acc.z = hv.z * w; acc.w = hv.w * w;
    }
    int e0 = row_ptr[node], e1 = row_ptr[node + 1];
    for (int e = e0; e < e1; ++e) {
        int s = csr_src[e];
        float w = csr_norm[e];
        if (act) {
            float4 hv = ((const float4*)(h + (size_t)s * FV * 4))[lane];
            acc.x = fmaf(w, hv.x, acc.x);
            acc.y = fmaf(w, hv.y, acc.y);
            acc.z = fmaf(w, hv.z, acc.z);
            acc.w = fmaf(w, hv.w, acc.w);
        }
    }
    if (act) {
        float4 b = ((const float4*)bias)[lane];
        float4 r = make_float4(acc.x + b.x, acc.y + b.y, acc.z + b.z, acc.w + b.w);
        ((float4*)(out + (size_t)node * FV * 4))[lane] = r;
    }
}

// ---------------- GEMM: Y[r, ocol + c] = sum_k X[r,k] * W[k,c], K fixed 128 ----------------
// Block: 256 threads, 64 rows x (CG*4) cols. K chunked by 32 (24KB LDS max).
template <int CG, int RPT>
__global__ __launch_bounds__(256) void gemm_kernel(const float* __restrict__ X,
                                                   const float* __restrict__ W,
                                                   float* __restrict__ Y, int nrows, int fout,
                                                   int ostride, int ocol) {
    __shared__ float Ws[32][CG * 4];
    __shared__ float Xs[64][32];
    int tid = threadIdx.x;
    int row0 = blockIdx.x * 64;
    int cg = tid % CG;
    int rg = tid / CG;
    float4 acc[RPT];
#pragma unroll
    for (int i = 0; i < RPT; ++i) acc[i] = make_float4(0.f, 0.f, 0.f, 0.f);
    for (int kc = 0; kc < 4; ++kc) {
        for (int i = tid; i < 32 * CG; i += 256) {
            int r = i / CG, c = i % CG;
            float4 w;
            if ((c * 4 + 3) < fout) {
                w = *(const float4*)(W + (size_t)(kc * 32 + r) * fout + c * 4);
            } else {
                float t0 = (c * 4 + 0) < fout ? W[(size_t)(kc * 32 + r) * fout + c * 4 + 0] : 0.f;
                float t1 = (c * 4 + 1) < fout ? W[(size_t)(kc * 32 + r) * fout + c * 4 + 1] : 0.f;
                float t2 = (c * 4 + 2) < fout ? W[(size_t)(kc * 32 + r) * fout + c * 4 + 2] : 0.f;
                float t3 = (c * 4 + 3) < fout ? W[(size_t)(kc * 32 + r) * fout + c * 4 + 3] : 0.f;
                w = make_float4(t0, t1, t2, t3);
            }
            *(float4*)&Ws[r][c * 4] = w;
        }
        for (int i = tid; i < 64 * 8; i += 256) {
            int r = i / 8, c = i % 8;
            int gr = row0 + r;
            float4 v = make_float4(0.f, 0.f, 0.f, 0.f);
            if (gr < nrows) v = *(const float4*)(X + (size_t)gr * DFEAT + kc * 32 + c * 4);
            *(float4*)&Xs[r][c * 4] = v;
        }
        __syncthreads();
#pragma unroll
        for (int k = 0; k < 32; ++k) {
            float4 w = *(float4*)&Ws[k][cg * 4];
#pragma unroll
            for (int i = 0; i < RPT; ++i) {
                float a = Xs[rg * RPT + i][k];
                acc[i].x = fmaf(a, w.x, acc[i].x);
                acc[i].y = fmaf(a, w.y, acc[i].y);
                acc[i].z = fmaf(a, w.z, acc[i].z);
                acc[i].w = fmaf(a, w.w, acc[i].w);
            }
        }
        __syncthreads();
    }
    if (cg * 4 < fout) {
#pragma unroll
        for (int i = 0; i < RPT; ++i) {
            int r = row0 + rg * RPT + i;
            if (r < nrows) *(float4*)(Y + (size_t)r * ostride + ocol + cg * 4) = acc[i];
        }
    }
}

// ---------------- BN statistics: per-column sum and sumsq ----------------
__global__ __launch_bounds__(128) void stats_kernel(const float* __restrict__ pre,
                                                    float* __restrict__ stats, int nrows) {
    int col = threadIdx.x;  // blockDim = 128
    int r0 = blockIdx.x * 512;
    int r1 = min(r0 + 512, nrows);
    float s = 0.f, s2 = 0.f;
    for (int r = r0; r < r1; ++r) {
        float v = pre[(size_t)r * DFEAT + col];
        s += v;
        s2 = fmaf(v, v, s2);
    }
    atomicAdd(&stats[col], s);
    atomicAdd(&stats[DFEAT + col], s2);
}

// ---------------- BN scale/shift + sigmoid gates from row N-1 ----------------
__global__ __launch_bounds__(128) void gate_prep_kernel(
    const float* __restrict__ statsA, const float* __restrict__ statsB,
    const float* __restrict__ preA, const float* __restrict__ preB,
    const float* __restrict__ gamma, const float* __restrict__ beta,
    const float* __restrict__ gwA, const float* __restrict__ gbA,
    const float* __restrict__ gwB, const float* __restrict__ gbB,
    float* __restrict__ ss, float* __restrict__ wout, int nrows) {
    __shared__ float red[128];
    __shared__ float dotA_s;
    int t = threadIdx.x;
    float invN = 1.f / (float)nrows;
    float meanA = statsA[t] * invN;
    float varA = statsA[DFEAT + t] * invN - meanA * meanA;
    float scA = gamma[t] * rsqrtf(varA + 1e-5f);
    float shA = beta[t] - meanA * scA;
    ss[t] = scA;
    ss[DFEAT + t] = shA;
    float meanB = statsB[t] * invN;
    float varB = statsB[DFEAT + t] * invN - meanB * meanB;
    float scB = gamma[t] * rsqrtf(varB + 1e-5f);
    float shB = beta[t] - meanB * scB;
    ss[2 * DFEAT + t] = scB;
    ss[3 * DFEAT + t] = shB;
    float av = fmaxf(fmaf(preA[(size_t)(nrows - 1) * DFEAT + t], scA, shA), 0.f);
    red[t] = av * gwA[t];
    __syncthreads();
    for (int s = 64; s > 0; s >>= 1) {
        if (t < s) red[t] += red[t + s];
        __syncthreads();
    }
    if (t == 0) dotA_s = red[0];
    __syncthreads();
    float bv = fmaxf(fmaf(preB[(size_t)(nrows - 1) * DFEAT + t], scB, shB), 0.f);
    red[t] = bv * gwB[t];
    __syncthreads();
    for (int s = 64; s > 0; s >>= 1) {
        if (t < s) red[t] += red[t + s];
        __syncthreads();
    }
    if (t == 0) {
        float s1 = 1.f / (1.f + expf(-(dotA_s + gbA[0])));
        float s2 = 1.f / (1.f + expf(-(red[0] + gbB[0])));
        float tt = s1 + s2;
        wout[0] = s1 / tt;
        wout[1] = s2 / tt;
    }
}

// gates for the final layer (no BN), F = nclass
__global__ __launch_bounds__(64) void gate_final_kernel(
    const float* __restrict__ p1, const float* __restrict__ p2,
    const float* __restrict__ w1v, const float* __restrict__ b1,
    const float* __restrict__ w2v, const float* __restrict__ b2,
    float* __restrict__ wout, int nrows, int nclass) {
    __shared__ float red[64];
    __shared__ float dot1_s;
    int t = threadIdx.x;
    float v = (t < nclass) ? p1[(size_t)(nrows - 1) * nclass + t] * w1v[t] : 0.f;
    red[t] = v;
    __syncthreads();
    for (int s = 32; s > 0; s >>= 1) {
        if (t < s) red[t] += red[t + s];
        __syncthreads();
    }
    if (t == 0) dot1_s = red[0];
    __syncthreads();
    v = (t < nclass) ? p2[(size_t)(nrows - 1) * nclass + t] * w2v[t] : 0.f;
    red[t] = v;
    __syncthreads();
    for (int s = 32; s > 0; s >>= 1) {
        if (t < s) red[t] += red[t + s];
        __syncthreads();
    }
    if (t == 0) {
        float s1 = 1.f / (1.f + expf(-(dot1_s + b1[0])));
        float s2 = 1.f / (1.f + expf(-(red[0] + b2[0])));
        float tt = s1 + s2;
        wout[0] = s1 / tt;
        wout[1] = s2 / tt;
    }
}

// ---------------- combine: X = w1*relu(bn(A)) + w2*relu(bn(B)) ----------------
__global__ __launch_bounds__(256) void combine_kernel(const float* __restrict__ A,
                                                      const float* __restrict__ B,
                                                      const float* __restrict__ ss,
                                                      const float* __restrict__ wout,
                                                      float* __restrict__ X, int n4) {
    int idx = blockIdx.x * blockDim.x + threadIdx.x;
    if (idx >= n4) return;
    int c = (idx & 31) * 4;
    float4 a = *(const float4*)(A + (size_t)idx * 4);
    float4 b = *(const float4*)(B + (size_t)idx * 4);
    float4 scA = *(const float4*)(ss + c);
    float4 shA = *(const float4*)(ss + DFEAT + c);
    float4 scB = *(const float4*)(ss + 2 * DFEAT + c);
    float4 shB = *(const float4*)(ss + 3 * DFEAT + c);
    float w1 = wout[0], w2 = wout[1];
    float4 r;
    r.x = w1 * fmaxf(fmaf(a.x, scA.x, shA.x), 0.f) + w2 * fmaxf(fmaf(b.x, scB.x, shB.x), 0.f);
    r.y = w1 * fmaxf(fmaf(a.y, scA.y, shA.y), 0.f) + w2 * fmaxf(fmaf(b.y, scB.y, shB.y), 0.f);
    r.z = w1 * fmaxf(fmaf(a.z, scA.z, shA.z), 0.f) + w2 * fmaxf(fmaf(b.z, scB.z, shB.z), 0.f);
    r.w = w1 * fmaxf(fmaf(a.w, scA.w, shA.w), 0.f) + w2 * fmaxf(fmaf(b.w, scB.w, shB.w), 0.f);
    *(float4*)(X + (size_t)idx * 4) = r;
}

__global__ __launch_bounds__(256) void mix_kernel(const float* __restrict__ p1,
                                                  const float* __restrict__ p2,
                                                  const float* __restrict__ wout,
                                                  float* __restrict__ o, int n4) {
    int idx = blockIdx.x * blockDim.x + threadIdx.x;
    if (idx >= n4) return;
    float w1 = wout[0], w2 = wout[1];
    float4 a = *(const float4*)(p1 + (size_t)idx * 4);
    float4 b = *(const float4*)(p2 + (size_t)idx * 4);
    float4 r = make_float4(w1 * a.x + w2 * b.x, w1 * a.y + w2 * b.y, w1 * a.z + w2 * b.z,
                           w1 * a.w + w2 * b.w);
    *(float4*)(o + (size_t)idx * 4) = r;
}

extern "C" void kernel_launch(void* const* d_in, const int* in_sizes, int n_in, void* d_out,
                              int out_size, void* d_ws, size_t ws_size, hipStream_t stream) {
    (void)n_in; (void)out_size; (void)ws_size;
    const int N = in_sizes[0] / DFEAT;        // 50000
    const int E = in_sizes[4] / 2;            // 800000
    const int NC = in_sizes[15];              // 40

    const float* x1a = (const float*)d_in[0];
    const float* x1b = (const float*)d_in[1];
    const float* x2a = (const float*)d_in[2];
    const float* x2b = (const float*)d_in[3];
    const int* ei1 = (const int*)d_in[4];
    const int* ei2 = (const int*)d_in[5];
    const float* Wi = (const float*)d_in[6];      // (2,128,64)
    const float* bi = (const float*)d_in[7];      // (2,64) flat = concat bias
    const float* gi = (const float*)d_in[8];
    const float* bei = (const float*)d_in[9];
    const float* Wm = (const float*)d_in[10];     // (2,128,128)
    const float* bm = (const float*)d_in[11];
    const float* gm = (const float*)d_in[12];
    const float* bem = (const float*)d_in[13];
    const float* Wf = (const float*)d_in[14];     // (128,40)
    const float* bf = (const float*)d_in[15];
    const float* fc1w1_W = (const float*)d_in[16];
    const float* fc1w1_b = (const float*)d_in[17];
    const float* fc1w2_W = (const float*)d_in[18];
    const float* fc1w2_b = (const float*)d_in[19];
    const float* aws_w1_W = (const float*)d_in[20];
    const float* aws_w1_b = (const float*)d_in[21];
    const float* aws_w2_W = (const float*)d_in[22];
    const float* aws_w2_b = (const float*)d_in[23];
    const float* fcw1_W = (const float*)d_in[24];
    const float* fcw1_b = (const float*)d_in[25];
    const float* fcw2_W = (const float*)d_in[26];
    const float* fcw2_b = (const float*)d_in[27];

    char* ws = (char*)d_ws;
    size_t off = 0;
    auto alloc = [&](size_t bytes) -> char* {
        char* p = ws + off;
        off += (bytes + 255) & ~(size_t)255;
        return p;
    };
    float* P = (float*)alloc((size_t)N * DFEAT * 4);
    float* Q = (float*)alloc((size_t)N * DFEAT * 4);
    float* R = (float*)alloc((size_t)N * DFEAT * 4);
    int* rp1 = (int*)alloc((size_t)(N + 1) * 4);
    int* cnt1 = (int*)alloc((size_t)N * 4);
    int* fl1 = (int*)alloc((size_t)N * 4);
    float* dv1 = (float*)alloc((size_t)N * 4);
    int* cs1 = (int*)alloc((size_t)E * 4);
    float* cn1 = (float*)alloc((size_t)E * 4);
    int* rp2 = (int*)alloc((size_t)(N + 1) * 4);
    int* cnt2 = (int*)alloc((size_t)N * 4);
    int* fl2 = (int*)alloc((size_t)N * 4);
    float* dv2 = (float*)alloc((size_t)N * 4);
    int* cs2 = (int*)alloc((size_t)E * 4);
    float* cn2 = (float*)alloc((size_t)E * 4);
    float* stats = (float*)alloc(2048);  // statsA (256) + statsB (256)
    float* statsA = stats;
    float* statsB = stats + 256;
    float* ssbuf = (float*)alloc(2048);  // scaleA, shiftA, scaleB, shiftB
    float* wout = (float*)alloc(256);

    const int* src1 = ei1;
    const int* dst1 = ei1 + E;
    const int* src2 = ei2;
    const int* dst2 = ei2 + E;

    int ebl = (E + 255) / 256;
    int gemmbl = (N + 63) / 64;
    int aggbl128 = (N * 32 + 255) / 256;
    int aggbl40 = (N * 16 + 255) / 256;
    int statbl = (N + 511) / 512;
    int combbl = (N * 32 + 255) / 256;

    // ---- CSR build ----
    hipMemsetAsync(cnt1, 0, (size_t)N * 4, stream);
    hipMemsetAsync(fl1, 0, (size_t)N * 4, stream);
    hipMemsetAsync(cnt2, 0, (size_t)N * 4, stream);
    hipMemsetAsync(fl2, 0, (size_t)N * 4, stream);
    count_kernel<<<ebl, 256, 0, stream>>>(dst1, cnt1, E);
    count_kernel<<<ebl, 256, 0, stream>>>(dst2, cnt2, E);
    scan_kernel<<<1, 1024, 0, stream>>>(cnt1, rp1, dv1, N);
    scan_kernel<<<1, 1024, 0, stream>>>(cnt2, rp2, dv2, N);
    fill_kernel<<<ebl, 256, 0, stream>>>(src1, dst1, rp1, fl1, cs1, cn1, dv1, E);
    fill_kernel<<<ebl, 256, 0, stream>>>(src2, dst2, rp2, fl2, cs2, cn2, dv2, E);

    // ---- Layer 1: h = concat halves ----
    gemm_kernel<16, 4><<<gemmbl, 256, 0, stream>>>(x1a, Wi, P, N, 64, DFEAT, 0);
    gemm_kernel<16, 4><<<gemmbl, 256, 0, stream>>>(x1b, Wi + 128 * 64, P, N, 64, DFEAT, 64);
    gemm_kernel<16, 4><<<gemmbl, 256, 0, stream>>>(x2a, Wi, Q, N, 64, DFEAT, 0);
    gemm_kernel<16, 4><<<gemmbl, 256, 0, stream>>>(x2b, Wi + 128 * 64, Q, N, 64, DFEAT, 64);
    agg_kernel<32, 32><<<aggbl128, 256, 0, stream>>>(P, rp1, cs1, cn1, dv1, bi, R, N);  // pre1 -> R
    agg_kernel<32, 32><<<aggbl128, 256, 0, stream>>>(Q, rp2, cs2, cn2, dv2, bi, P, N);  // pre2 -> P
    hipMemsetAsync(stats, 0, 2048, stream);
    stats_kernel<<<statbl, 128, 0, stream>>>(R, statsA, N);
    stats_kernel<<<statbl, 128, 0, stream>>>(P, statsB, N);
    gate_prep_kernel<<<1, 128, 0, stream>>>(statsA, statsB, R, P, gi, bei, fc1w1_W, fc1w1_b,
                                            fc1w2_W, fc1w2_b, ssbuf, wout, N);
    combine_kernel<<<combbl, 256, 0, stream>>>(R, P, ssbuf, wout, Q, N * 32);  // X -> Q

    // ---- Middle layers ----
    // i=0: X in Q
    gemm_kernel<32, 8><<<gemmbl, 256, 0, stream>>>(Q, Wm, P, N, 128, 128, 0);
    agg_kernel<32, 32><<<aggbl128, 256, 0, stream>>>(P, rp1, cs1, cn1, dv1, bm, Q, N);
    agg_kernel<32, 32><<<aggbl128, 256, 0, stream>>>(P, rp2, cs2, cn2, dv2, bm, R, N);
    hipMemsetAsync(stats, 0, 2048, stream);
    stats_kernel<<<statbl, 128, 0, stream>>>(Q, statsA, N);
    stats_kernel<<<statbl, 128, 0, stream>>>(R, statsB, N);
    gate_prep_kernel<<<1, 128, 0, stream>>>(statsA, statsB, Q, R, gm, bem, aws_w1_W, aws_w1_b,
                                            aws_w2_W, aws_w2_b, ssbuf, wout, N);
    combine_kernel<<<combbl, 256, 0, stream>>>(Q, R, ssbuf, wout, P, N * 32);  // X -> P

    // i=1: X in P
    gemm_kernel<32, 8><<<gemmbl, 256, 0, stream>>>(P, Wm + 128 * 128, Q, N, 128, 128, 0);
    agg_kernel<32, 32><<<aggbl128, 256, 0, stream>>>(Q, rp1, cs1, cn1, dv1, bm + 128, P, N);
    agg_kernel<32, 32><<<aggbl128, 256, 0, stream>>>(Q, rp2, cs2, cn2, dv2, bm + 128, R, N);
    hipMemsetAsync(stats, 0, 2048, stream);
    stats_kernel<<<statbl, 128, 0, stream>>>(P, statsA, N);
    stats_kernel<<<statbl, 128, 0, stream>>>(R, statsB, N);
    gate_prep_kernel<<<1, 128, 0, stream>>>(statsA, statsB, P, R, gm + 128, bem + 128,
                                            aws_w1_W + 128, aws_w1_b + 1, aws_w2_W + 128,
                                            aws_w2_b + 1, ssbuf, wout, N);
    combine_kernel<<<combbl, 256, 0, stream>>>(P, R, ssbuf, wout, Q, N * 32);  // X -> Q

    // ---- Final layer ----
    float* out0 = (float*)d_out;
    float* p1 = out0 + (size_t)N * NC;
    float* p2 = out0 + (size_t)2 * N * NC;
    gemm_kernel<16, 4><<<gemmbl, 256, 0, stream>>>(Q, Wf, P, N, NC, NC, 0);  // HF -> P (N x 40)
    agg_kernel<10, 16><<<aggbl40, 256, 0, stream>>>(P, rp1, cs1, cn1, dv1, bf, p1, N);
    agg_kernel<10, 16><<<aggbl40, 256, 0, stream>>>(P, rp2, cs2, cn2, dv2, bf, p2, N);
    gate_final_kernel<<<1, 64, 0, stream>>>(p1, p2, fcw1_W, fcw1_b, fcw2_W, fcw2_b, wout, N, NC);
    mix_kernel<<<(N * NC / 4 + 255) / 256, 256, 0, stream>>>(p1, p2, wout, out0, N * NC / 4);
}

// Round 2
// 1262.438 us; speedup vs baseline: 1.5678x; 1.5678x over previous
//
#include <hip/hip_runtime.h>

// CLAGCN forward on MI355X.
// R1: stats_kernel was 6 x 128us at 2% occupancy (98 blocks x 128 thr).
//     Replaced with 2-level reduction: (N/128) x 2 blocks x 256 thr,
//     LDS block-reduce + 1 atomicAdd/column/block. Also unrolled agg edge
//     loop by 4 to get independent gathers in flight.

#define DFEAT 128

// ---------------- CSR build ----------------
__global__ void count_kernel(const int* __restrict__ dst, int* __restrict__ counts, int E) {
    int i = blockIdx.x * blockDim.x + threadIdx.x;
    if (i < E) atomicAdd(&counts[dst[i]], 1);
}

__global__ __launch_bounds__(1024) void scan_kernel(const int* __restrict__ counts,
                                                    int* __restrict__ row_ptr,
                                                    float* __restrict__ dinv, int n) {
    const int T = 1024;
    int t = threadIdx.x;
    int C = (n + T - 1) / T;
    int lo = t * C;
    int hi = min(lo + C, n);
    int sum = 0;
    for (int i = lo; i < hi; ++i) sum += counts[i];
    __shared__ int buf[T];
    buf[t] = sum;
    __syncthreads();
    for (int off = 1; off < T; off <<= 1) {
        int x = (t >= off) ? buf[t - off] : 0;
        __syncthreads();
        buf[t] += x;
        __syncthreads();
    }
    int run = buf[t] - sum;  // exclusive prefix of this thread's chunk
    for (int i = lo; i < hi; ++i) {
        int v = counts[i];
        row_ptr[i] = run;
        dinv[i] = rsqrtf((float)(v + 1));  // +1 self-loop; deg>=1 always
        run += v;
    }
    if (t == T - 1) row_ptr[n] = run;
}

__global__ void fill_kernel(const int* __restrict__ src, const int* __restrict__ dst,
                            const int* __restrict__ row_ptr, int* __restrict__ fill,
                            int* __restrict__ csr_src, float* __restrict__ csr_norm,
                            const float* __restrict__ dinv, int E) {
    int i = blockIdx.x * blockDim.x + threadIdx.x;
    if (i >= E) return;
    int d = dst[i];
    int s = src[i];
    int pos = row_ptr[d] + atomicAdd(&fill[d], 1);
    csr_src[pos] = s;
    csr_norm[pos] = dinv[s] * dinv[d];
}

// ---------------- aggregation (gather over CSR) ----------------
// One GROUP of lanes per node; lane handles float4 column chunk. Self-loop folded in.
// Edge loop unrolled x4: indices/norms loaded as a batch so 4 row-gathers are
// independent (the serial dependent-load chain was the latency bottleneck).
template <int FV, int GROUP>
__global__ void agg_kernel(const float* __restrict__ h, const int* __restrict__ row_ptr,
                           const int* __restrict__ csr_src, const float* __restrict__ csr_norm,
                           const float* __restrict__ dinv, const float* __restrict__ bias,
                           float* __restrict__ out, int n) {
    int gid = (blockIdx.x * blockDim.x + threadIdx.x) / GROUP;
    int lane = threadIdx.x & (GROUP - 1);
    if (gid >= n) return;
    int node = gid;
    bool act = (lane < FV);
    float dn = dinv[node];
    float4 acc = make_float4(0.f, 0.f, 0.f, 0.f);
    if (act) {
        float4 hv = ((const float4*)(h + (size_t)node * FV * 4))[lane];
        float w = dn * dn;  // self-loop norm
        acc.x = hv.x * w; acc.y = hv.y * w; acc.z = hv.z * w; acc.w = hv.w * w;
    }
    int e0 = row_ptr[node], e1 = row_ptr[node + 1];
    int e = e0;
    for (; e + 4 <= e1; e += 4) {
        int s0 = csr_src[e + 0], s1 = csr_src[e + 1];
        int s2 = csr_src[e + 2], s3 = csr_src[e + 3];
        float w0 = csr_norm[e + 0], w1 = csr_norm[e + 1];
        float w2 = csr_norm[e + 2], w3 = csr_norm[e + 3];
        if (act) {
            float4 h0 = ((const float4*)(h + (size_t)s0 * FV * 4))[lane];
            float4 h1 = ((const float4*)(h + (size_t)s1 * FV * 4))[lane];
            float4 h2 = ((const float4*)(h + (size_t)s2 * FV * 4))[lane];
            float4 h3 = ((const float4*)(h + (size_t)s3 * FV * 4))[lane];
            acc.x = fmaf(w0, h0.x, acc.x); acc.y = fmaf(w0, h0.y, acc.y);
            acc.z = fmaf(w0, h0.z, acc.z); acc.w = fmaf(w0, h0.w, acc.w);
            acc.x = fmaf(w1, h1.x, acc.x); acc.y = fmaf(w1, h1.y, acc.y);
            acc.z = fmaf(w1, h1.z, acc.z); acc.w = fmaf(w1, h1.w, acc.w);
            acc.x = fmaf(w2, h2.x, acc.x); acc.y = fmaf(w2, h2.y, acc.y);
            acc.z = fmaf(w2, h2.z, acc.z); acc.w = fmaf(w2, h2.w, acc.w);
            acc.x = fmaf(w3, h3.x, acc.x); acc.y = fmaf(w3, h3.y, acc.y);
            acc.z = fmaf(w3, h3.z, acc.z); acc.w = fmaf(w3, h3.w, acc.w);
        }
    }
    for (; e < e1; ++e) {
        int s = csr_src[e];
        float w = csr_norm[e];
        if (act) {
            float4 hv = ((const float4*)(h + (size_t)s * FV * 4))[lane];
            acc.x = fmaf(w, hv.x, acc.x);
            acc.y = fmaf(w, hv.y, acc.y);
            acc.z = fmaf(w, hv.z, acc.z);
            acc.w = fmaf(w, hv.w, acc.w);
        }
    }
    if (act) {
        float4 b = ((const float4*)bias)[lane];
        float4 r = make_float4(acc.x + b.x, acc.y + b.y, acc.z + b.z, acc.w + b.w);
        ((float4*)(out + (size_t)node * FV * 4))[lane] = r;
    }
}

// ---------------- GEMM: Y[r, ocol + c] = sum_k X[r,k] * W[k,c], K fixed 128 ----------------
// Block: 256 threads, 64 rows x (CG*4) cols. K chunked by 32 (24KB LDS max).
template <int CG, int RPT>
__global__ __launch_bounds__(256) void gemm_kernel(const float* __restrict__ X,
                                                   const float* __restrict__ W,
                                                   float* __restrict__ Y, int nrows, int fout,
                                                   int ostride, int ocol) {
    __shared__ float Ws[32][CG * 4];
    __shared__ float Xs[64][32];
    int tid = threadIdx.x;
    int row0 = blockIdx.x * 64;
    int cg = tid % CG;
    int rg = tid / CG;
    float4 acc[RPT];
#pragma unroll
    for (int i = 0; i < RPT; ++i) acc[i] = make_float4(0.f, 0.f, 0.f, 0.f);
    for (int kc = 0; kc < 4; ++kc) {
        for (int i = tid; i < 32 * CG; i += 256) {
            int r = i / CG, c = i % CG;
            float4 w;
            if ((c * 4 + 3) < fout) {
                w = *(const float4*)(W + (size_t)(kc * 32 + r) * fout + c * 4);
            } else {
                float t0 = (c * 4 + 0) < fout ? W[(size_t)(kc * 32 + r) * fout + c * 4 + 0] : 0.f;
                float t1 = (c * 4 + 1) < fout ? W[(size_t)(kc * 32 + r) * fout + c * 4 + 1] : 0.f;
                float t2 = (c * 4 + 2) < fout ? W[(size_t)(kc * 32 + r) * fout + c * 4 + 2] : 0.f;
                float t3 = (c * 4 + 3) < fout ? W[(size_t)(kc * 32 + r) * fout + c * 4 + 3] : 0.f;
                w = make_float4(t0, t1, t2, t3);
            }
            *(float4*)&Ws[r][c * 4] = w;
        }
        for (int i = tid; i < 64 * 8; i += 256) {
            int r = i / 8, c = i % 8;
            int gr = row0 + r;
            float4 v = make_float4(0.f, 0.f, 0.f, 0.f);
            if (gr < nrows) v = *(const float4*)(X + (size_t)gr * DFEAT + kc * 32 + c * 4);
            *(float4*)&Xs[r][c * 4] = v;
        }
        __syncthreads();
#pragma unroll
        for (int k = 0; k < 32; ++k) {
            float4 w = *(float4*)&Ws[k][cg * 4];
#pragma unroll
            for (int i = 0; i < RPT; ++i) {
                float a = Xs[rg * RPT + i][k];
                acc[i].x = fmaf(a, w.x, acc[i].x);
                acc[i].y = fmaf(a, w.y, acc[i].y);
                acc[i].z = fmaf(a, w.z, acc[i].z);
                acc[i].w = fmaf(a, w.w, acc[i].w);
            }
        }
        __syncthreads();
    }
    if (cg * 4 < fout) {
#pragma unroll
        for (int i = 0; i < RPT; ++i) {
            int r = row0 + rg * RPT + i;
            if (r < nrows) *(float4*)(Y + (size_t)r * ostride + ocol + cg * 4) = acc[i];
        }
    }
}

// ---------------- BN statistics: per-column sum and sumsq (2-level) ----------------
// grid: (ceil(N/128), 2). blockIdx.y selects buffer A/B. 256 threads = 2 row-groups
// of 128 cols; each thread accumulates 64 rows, LDS-reduce, 1 atomicAdd/col/block.
__global__ __launch_bounds__(256) void stats2_kernel(const float* __restrict__ A,
                                                     const float* __restrict__ B,
                                                     float* __restrict__ stats, int nrows) {
    __shared__ float red1[256];
    __shared__ float red2[256];
    int t = threadIdx.x;
    int col = t & 127;
    int rg = t >> 7;  // 0 or 1
    const float* src = (blockIdx.y == 0) ? A : B;
    float* st = stats + (size_t)blockIdx.y * 256;
    int r0 = blockIdx.x * 128 + rg * 64;
    int r1 = min(r0 + 64, nrows);
    float s = 0.f, s2 = 0.f;
    for (int r = r0; r < r1; ++r) {
        float v = src[(size_t)r * DFEAT + col];
        s += v;
        s2 = fmaf(v, v, s2);
    }
    red1[t] = s;
    red2[t] = s2;
    __syncthreads();
    if (t < 128) {
        float fs = red1[t] + red1[t + 128];
        float fs2 = red2[t] + red2[t + 128];
        atomicAdd(&st[col], fs);
        atomicAdd(&st[DFEAT + col], fs2);
    }
}

// ---------------- BN scale/shift + sigmoid gates from row N-1 ----------------
__global__ __launch_bounds__(128) void gate_prep_kernel(
    const float* __restrict__ statsA, const float* __restrict__ statsB,
    const float* __restrict__ preA, const float* __restrict__ preB,
    const float* __restrict__ gamma, const float* __restrict__ beta,
    const float* __restrict__ gwA, const float* __restrict__ gbA,
    const float* __restrict__ gwB, const float* __restrict__ gbB,
    float* __restrict__ ss, float* __restrict__ wout, int nrows) {
    __shared__ float red[128];
    __shared__ float dotA_s;
    int t = threadIdx.x;
    float invN = 1.f / (float)nrows;
    float meanA = statsA[t] * invN;
    float varA = statsA[DFEAT + t] * invN - meanA * meanA;
    float scA = gamma[t] * rsqrtf(varA + 1e-5f);
    float shA = beta[t] - meanA * scA;
    ss[t] = scA;
    ss[DFEAT + t] = shA;
    float meanB = statsB[t] * invN;
    float varB = statsB[DFEAT + t] * invN - meanB * meanB;
    float scB = gamma[t] * rsqrtf(varB + 1e-5f);
    float shB = beta[t] - meanB * scB;
    ss[2 * DFEAT + t] = scB;
    ss[3 * DFEAT + t] = shB;
    float av = fmaxf(fmaf(preA[(size_t)(nrows - 1) * DFEAT + t], scA, shA), 0.f);
    red[t] = av * gwA[t];
    __syncthreads();
    for (int s = 64; s > 0; s >>= 1) {
        if (t < s) red[t] += red[t + s];
        __syncthreads();
    }
    if (t == 0) dotA_s = red[0];
    __syncthreads();
    float bv = fmaxf(fmaf(preB[(size_t)(nrows - 1) * DFEAT + t], scB, shB), 0.f);
    red[t] = bv * gwB[t];
    __syncthreads();
    for (int s = 64; s > 0; s >>= 1) {
        if (t < s) red[t] += red[t + s];
        __syncthreads();
    }
    if (t == 0) {
        float s1 = 1.f / (1.f + expf(-(dotA_s + gbA[0])));
        float s2 = 1.f / (1.f + expf(-(red[0] + gbB[0])));
        float tt = s1 + s2;
        wout[0] = s1 / tt;
        wout[1] = s2 / tt;
    }
}

// gates for the final layer (no BN), F = nclass
__global__ __launch_bounds__(64) void gate_final_kernel(
    const float* __restrict__ p1, const float* __restrict__ p2,
    const float* __restrict__ w1v, const float* __restrict__ b1,
    const float* __restrict__ w2v, const float* __restrict__ b2,
    float* __restrict__ wout, int nrows, int nclass) {
    __shared__ float red[64];
    __shared__ float dot1_s;
    int t = threadIdx.x;
    float v = (t < nclass) ? p1[(size_t)(nrows - 1) * nclass + t] * w1v[t] : 0.f;
    red[t] = v;
    __syncthreads();
    for (int s = 32; s > 0; s >>= 1) {
        if (t < s) red[t] += red[t + s];
        __syncthreads();
    }
    if (t == 0) dot1_s = red[0];
    __syncthreads();
    v = (t < nclass) ? p2[(size_t)(nrows - 1) * nclass + t] * w2v[t] : 0.f;
    red[t] = v;
    __syncthreads();
    for (int s = 32; s > 0; s >>= 1) {
        if (t < s) red[t] += red[t + s];
        __syncthreads();
    }
    if (t == 0) {
        float s1 = 1.f / (1.f + expf(-(dot1_s + b1[0])));
        float s2 = 1.f / (1.f + expf(-(red[0] + b2[0])));
        float tt = s1 + s2;
        wout[0] = s1 / tt;
        wout[1] = s2 / tt;
    }
}

// ---------------- combine: X = w1*relu(bn(A)) + w2*relu(bn(B)) ----------------
__global__ __launch_bounds__(256) void combine_kernel(const float* __restrict__ A,
                                                      const float* __restrict__ B,
                                                      const float* __restrict__ ss,
                                                      const float* __restrict__ wout,
                                                      float* __restrict__ X, int n4) {
    int idx = blockIdx.x * blockDim.x + threadIdx.x;
    if (idx >= n4) return;
    int c = (idx & 31) * 4;
    float4 a = *(const float4*)(A + (size_t)idx * 4);
    float4 b = *(const float4*)(B + (size_t)idx * 4);
    float4 scA = *(const float4*)(ss + c);
    float4 shA = *(const float4*)(ss + DFEAT + c);
    float4 scB = *(const float4*)(ss + 2 * DFEAT + c);
    float4 shB = *(const float4*)(ss + 3 * DFEAT + c);
    float w1 = wout[0], w2 = wout[1];
    float4 r;
    r.x = w1 * fmaxf(fmaf(a.x, scA.x, shA.x), 0.f) + w2 * fmaxf(fmaf(b.x, scB.x, shB.x), 0.f);
    r.y = w1 * fmaxf(fmaf(a.y, scA.y, shA.y), 0.f) + w2 * fmaxf(fmaf(b.y, scB.y, shB.y), 0.f);
    r.z = w1 * fmaxf(fmaf(a.z, scA.z, shA.z), 0.f) + w2 * fmaxf(fmaf(b.z, scB.z, shB.z), 0.f);
    r.w = w1 * fmaxf(fmaf(a.w, scA.w, shA.w), 0.f) + w2 * fmaxf(fmaf(b.w, scB.w, shB.w), 0.f);
    *(float4*)(X + (size_t)idx * 4) = r;
}

__global__ __launch_bounds__(256) void mix_kernel(const float* __restrict__ p1,
                                                  const float* __restrict__ p2,
                                                  const float* __restrict__ wout,
                                                  float* __restrict__ o, int n4) {
    int idx = blockIdx.x * blockDim.x + threadIdx.x;
    if (idx >= n4) return;
    float w1 = wout[0], w2 = wout[1];
    float4 a = *(const float4*)(p1 + (size_t)idx * 4);
    float4 b = *(const float4*)(p2 + (size_t)idx * 4);
    float4 r = make_float4(w1 * a.x + w2 * b.x, w1 * a.y + w2 * b.y, w1 * a.z + w2 * b.z,
                           w1 * a.w + w2 * b.w);
    *(float4*)(o + (size_t)idx * 4) = r;
}

extern "C" void kernel_launch(void* const* d_in, const int* in_sizes, int n_in, void* d_out,
                              int out_size, void* d_ws, size_t ws_size, hipStream_t stream) {
    (void)n_in; (void)out_size; (void)ws_size;
    const int N = in_sizes[0] / DFEAT;        // 50000
    const int E = in_sizes[4] / 2;            // 800000
    const int NC = in_sizes[15];              // 40

    const float* x1a = (const float*)d_in[0];
    const float* x1b = (const float*)d_in[1];
    const float* x2a = (const float*)d_in[2];
    const float* x2b = (const float*)d_in[3];
    const int* ei1 = (const int*)d_in[4];
    const int* ei2 = (const int*)d_in[5];
    const float* Wi = (const float*)d_in[6];      // (2,128,64)
    const float* bi = (const float*)d_in[7];      // (2,64) flat = concat bias
    const float* gi = (const float*)d_in[8];
    const float* bei = (const float*)d_in[9];
    const float* Wm = (const float*)d_in[10];     // (2,128,128)
    const float* bm = (const float*)d_in[11];
    const float* gm = (const float*)d_in[12];
    const float* bem = (const float*)d_in[13];
    const float* Wf = (const float*)d_in[14];     // (128,40)
    const float* bf = (const float*)d_in[15];
    const float* fc1w1_W = (const float*)d_in[16];
    const float* fc1w1_b = (const float*)d_in[17];
    const float* fc1w2_W = (const float*)d_in[18];
    const float* fc1w2_b = (const float*)d_in[19];
    const float* aws_w1_W = (const float*)d_in[20];
    const float* aws_w1_b = (const float*)d_in[21];
    const float* aws_w2_W = (const float*)d_in[22];
    const float* aws_w2_b = (const float*)d_in[23];
    const float* fcw1_W = (const float*)d_in[24];
    const float* fcw1_b = (const float*)d_in[25];
    const float* fcw2_W = (const float*)d_in[26];
    const float* fcw2_b = (const float*)d_in[27];

    char* ws = (char*)d_ws;
    size_t off = 0;
    auto alloc = [&](size_t bytes) -> char* {
        char* p = ws + off;
        off += (bytes + 255) & ~(size_t)255;
        return p;
    };
    float* P = (float*)alloc((size_t)N * DFEAT * 4);
    float* Q = (float*)alloc((size_t)N * DFEAT * 4);
    float* R = (float*)alloc((size_t)N * DFEAT * 4);
    int* rp1 = (int*)alloc((size_t)(N + 1) * 4);
    int* cnt1 = (int*)alloc((size_t)N * 4);
    int* fl1 = (int*)alloc((size_t)N * 4);
    float* dv1 = (float*)alloc((size_t)N * 4);
    int* cs1 = (int*)alloc((size_t)E * 4);
    float* cn1 = (float*)alloc((size_t)E * 4);
    int* rp2 = (int*)alloc((size_t)(N + 1) * 4);
    int* cnt2 = (int*)alloc((size_t)N * 4);
    int* fl2 = (int*)alloc((size_t)N * 4);
    float* dv2 = (float*)alloc((size_t)N * 4);
    int* cs2 = (int*)alloc((size_t)E * 4);
    float* cn2 = (float*)alloc((size_t)E * 4);
    float* stats = (float*)alloc(2048);  // statsA (256) + statsB (256)
    float* statsA = stats;
    float* statsB = stats + 256;
    float* ssbuf = (float*)alloc(2048);  // scaleA, shiftA, scaleB, shiftB
    float* wout = (float*)alloc(256);

    const int* src1 = ei1;
    const int* dst1 = ei1 + E;
    const int* src2 = ei2;
    const int* dst2 = ei2 + E;

    int ebl = (E + 255) / 256;
    int gemmbl = (N + 63) / 64;
    int aggbl128 = (N * 32 + 255) / 256;
    int aggbl40 = (N * 16 + 255) / 256;
    int combbl = (N * 32 + 255) / 256;
    dim3 statgrid((N + 127) / 128, 2);

    // ---- CSR build ----
    hipMemsetAsync(cnt1, 0, (size_t)N * 4, stream);
    hipMemsetAsync(fl1, 0, (size_t)N * 4, stream);
    hipMemsetAsync(cnt2, 0, (size_t)N * 4, stream);
    hipMemsetAsync(fl2, 0, (size_t)N * 4, stream);
    count_kernel<<<ebl, 256, 0, stream>>>(dst1, cnt1, E);
    count_kernel<<<ebl, 256, 0, stream>>>(dst2, cnt2, E);
    scan_kernel<<<1, 1024, 0, stream>>>(cnt1, rp1, dv1, N);
    scan_kernel<<<1, 1024, 0, stream>>>(cnt2, rp2, dv2, N);
    fill_kernel<<<ebl, 256, 0, stream>>>(src1, dst1, rp1, fl1, cs1, cn1, dv1, E);
    fill_kernel<<<ebl, 256, 0, stream>>>(src2, dst2, rp2, fl2, cs2, cn2, dv2, E);

    // ---- Layer 1: h = concat halves ----
    gemm_kernel<16, 4><<<gemmbl, 256, 0, stream>>>(x1a, Wi, P, N, 64, DFEAT, 0);
    gemm_kernel<16, 4><<<gemmbl, 256, 0, stream>>>(x1b, Wi + 128 * 64, P, N, 64, DFEAT, 64);
    gemm_kernel<16, 4><<<gemmbl, 256, 0, stream>>>(x2a, Wi, Q, N, 64, DFEAT, 0);
    gemm_kernel<16, 4><<<gemmbl, 256, 0, stream>>>(x2b, Wi + 128 * 64, Q, N, 64, DFEAT, 64);
    agg_kernel<32, 32><<<aggbl128, 256, 0, stream>>>(P, rp1, cs1, cn1, dv1, bi, R, N);  // pre1 -> R
    agg_kernel<32, 32><<<aggbl128, 256, 0, stream>>>(Q, rp2, cs2, cn2, dv2, bi, P, N);  // pre2 -> P
    hipMemsetAsync(stats, 0, 2048, stream);
    stats2_kernel<<<statgrid, 256, 0, stream>>>(R, P, stats, N);
    gate_prep_kernel<<<1, 128, 0, stream>>>(statsA, statsB, R, P, gi, bei, fc1w1_W, fc1w1_b,
                                            fc1w2_W, fc1w2_b, ssbuf, wout, N);
    combine_kernel<<<combbl, 256, 0, stream>>>(R, P, ssbuf, wout, Q, N * 32);  // X -> Q

    // ---- Middle layers ----
    // i=0: X in Q
    gemm_kernel<32, 8><<<gemmbl, 256, 0, stream>>>(Q, Wm, P, N, 128, 128, 0);
    agg_kernel<32, 32><<<aggbl128, 256, 0, stream>>>(P, rp1, cs1, cn1, dv1, bm, Q, N);
    agg_kernel<32, 32><<<aggbl128, 256, 0, stream>>>(P, rp2, cs2, cn2, dv2, bm, R, N);
    hipMemsetAsync(stats, 0, 2048, stream);
    stats2_kernel<<<statgrid, 256, 0, stream>>>(Q, R, stats, N);
    gate_prep_kernel<<<1, 128, 0, stream>>>(statsA, statsB, Q, R, gm, bem, aws_w1_W, aws_w1_b,
                                            aws_w2_W, aws_w2_b, ssbuf, wout, N);
    combine_kernel<<<combbl, 256, 0, stream>>>(Q, R, ssbuf, wout, P, N * 32);  // X -> P

    // i=1: X in P
    gemm_kernel<32, 8><<<gemmbl, 256, 0, stream>>>(P, Wm + 128 * 128, Q, N, 128, 128, 0);
    agg_kernel<32, 32><<<aggbl128, 256, 0, stream>>>(Q, rp1, cs1, cn1, dv1, bm + 128, P, N);
    agg_kernel<32, 32><<<aggbl128, 256, 0, stream>>>(Q, rp2, cs2, cn2, dv2, bm + 128, R, N);
    hipMemsetAsync(stats, 0, 2048, stream);
    stats2_kernel<<<statgrid, 256, 0, stream>>>(P, R, stats, N);
    gate_prep_kernel<<<1, 128, 0, stream>>>(statsA, statsB, P, R, gm + 128, bem + 128,
                                            aws_w1_W + 128, aws_w1_b + 1, aws_w2_W + 128,
                                            aws_w2_b + 1, ssbuf, wout, N);
    combine_kernel<<<combbl, 256, 0, stream>>>(P, R, ssbuf, wout, Q, N * 32);  // X -> Q

    // ---- Final layer ----
    float* out0 = (float*)d_out;
    float* p1 = out0 + (size_t)N * NC;
    float* p2 = out0 + (size_t)2 * N * NC;
    gemm_kernel<16, 4><<<gemmbl, 256, 0, stream>>>(Q, Wf, P, N, NC, NC, 0);  // HF -> P (N x 40)
    agg_kernel<10, 16><<<aggbl40, 256, 0, stream>>>(P, rp1, cs1, cn1, dv1, bf, p1, N);
    agg_kernel<10, 16><<<aggbl40, 256, 0, stream>>>(P, rp2, cs2, cn2, dv2, bf, p2, N);
    gate_final_kernel<<<1, 64, 0, stream>>>(p1, p2, fcw1_W, fcw1_b, fcw2_W, fcw2_b, wout, N, NC);
    mix_kernel<<<(N * NC / 4 + 255) / 256, 256, 0, stream>>>(p1, p2, wout, out0, N * NC / 4);
}

// Round 3
// 1065.380 us; speedup vs baseline: 1.8578x; 1.1850x over previous
//
#include <hip/hip_runtime.h>

// CLAGCN forward on MI355X.
// R1: stats_kernel 6x128us at 2% occupancy -> 2-level reduction (fixed).
// R2: scan_kernel was 2 x 110us single-block. Replaced with 3-phase
//     multi-block scan (blocksum -> tiny scan of block sums -> write
//     row_ptr/dinv), batched over both graphs via grid.y=2.

#define DFEAT 128

// ---------------- CSR build ----------------
__global__ void count_kernel(const int* __restrict__ dst, int* __restrict__ counts, int E) {
    int i = blockIdx.x * blockDim.x + threadIdx.x;
    if (i < E) atomicAdd(&counts[dst[i]], 1);
}

// Phase 1: per-block (2048 counts) sums. grid=(nb,2), 256 thr.
__global__ __launch_bounds__(256) void blocksum_kernel(const int* __restrict__ c1,
                                                       const int* __restrict__ c2,
                                                       int* __restrict__ bs, int n, int nb) {
    const int* c = blockIdx.y ? c2 : c1;
    int* out = bs + (size_t)blockIdx.y * nb;
    int t = threadIdx.x;
    int base = blockIdx.x * 2048 + t * 8;
    int s = 0;
#pragma unroll
    for (int i = 0; i < 8; ++i) {
        int idx = base + i;
        if (idx < n) s += c[idx];
    }
    __shared__ int red[256];
    red[t] = s;
    __syncthreads();
    for (int o = 128; o > 0; o >>= 1) {
        if (t < o) red[t] += red[t + o];
        __syncthreads();
    }
    if (t == 0) out[blockIdx.x] = red[0];
}

// Phase 2: exclusive scan of nb block sums per graph (nb ~ 25, serial per thread).
__global__ void scansums_kernel(int* __restrict__ bs, int nb, int* __restrict__ rp1,
                                int* __restrict__ rp2, int n, int E) {
    int t = threadIdx.x;
    if (t < 2) {
        int* b = bs + (size_t)t * nb;
        int run = 0;
        for (int i = 0; i < nb; ++i) {
            int v = b[i];
            b[i] = run;
            run += v;
        }
        (t ? rp2 : rp1)[n] = E;
    }
}

// Phase 3: block-local exclusive scan + block offset -> row_ptr, dinv. grid=(nb,2).
__global__ __launch_bounds__(256) void writerp_kernel(const int* __restrict__ c1,
                                                      const int* __restrict__ c2,
                                                      const int* __restrict__ bs,
                                                      int* __restrict__ rp1, int* __restrict__ rp2,
                                                      float* __restrict__ dv1,
                                                      float* __restrict__ dv2, int n, int nb) {
    const int* c = blockIdx.y ? c2 : c1;
    int* rp = blockIdx.y ? rp2 : rp1;
    float* dv = blockIdx.y ? dv2 : dv1;
    int boff = bs[(size_t)blockIdx.y * nb + blockIdx.x];
    int t = threadIdx.x;
    int base = blockIdx.x * 2048 + t * 8;
    int v[8];
    int s = 0;
#pragma unroll
    for (int i = 0; i < 8; ++i) {
        int idx = base + i;
        v[i] = (idx < n) ? c[idx] : 0;
        s += v[i];
    }
    __shared__ int red[256];
    red[t] = s;
    __syncthreads();
    for (int o = 1; o < 256; o <<= 1) {
        int x = (t >= o) ? red[t - o] : 0;
        __syncthreads();
        red[t] += x;
        __syncthreads();
    }
    int run = boff + red[t] - s;  // exclusive prefix for this thread's chunk
#pragma unroll
    for (int i = 0; i < 8; ++i) {
        int idx = base + i;
        if (idx < n) {
            rp[idx] = run;
            dv[idx] = rsqrtf((float)(v[i] + 1));  // +1 self-loop
            run += v[i];
        }
    }
}

__global__ void fill_kernel(const int* __restrict__ src, const int* __restrict__ dst,
                            const int* __restrict__ row_ptr, int* __restrict__ fill,
                            int* __restrict__ csr_src, float* __restrict__ csr_norm,
                            const float* __restrict__ dinv, int E) {
    int i = blockIdx.x * blockDim.x + threadIdx.x;
    if (i >= E) return;
    int d = dst[i];
    int s = src[i];
    int pos = row_ptr[d] + atomicAdd(&fill[d], 1);
    csr_src[pos] = s;
    csr_norm[pos] = dinv[s] * dinv[d];
}

// ---------------- aggregation (gather over CSR) ----------------
template <int FV, int GROUP>
__global__ void agg_kernel(const float* __restrict__ h, const int* __restrict__ row_ptr,
                           const int* __restrict__ csr_src, const float* __restrict__ csr_norm,
                           const float* __restrict__ dinv, const float* __restrict__ bias,
                           float* __restrict__ out, int n) {
    int gid = (blockIdx.x * blockDim.x + threadIdx.x) / GROUP;
    int lane = threadIdx.x & (GROUP - 1);
    if (gid >= n) return;
    int node = gid;
    bool act = (lane < FV);
    float dn = dinv[node];
    float4 acc = make_float4(0.f, 0.f, 0.f, 0.f);
    if (act) {
        float4 hv = ((const float4*)(h + (size_t)node * FV * 4))[lane];
        float w = dn * dn;  // self-loop norm
        acc.x = hv.x * w; acc.y = hv.y * w; acc.z = hv.z * w; acc.w = hv.w * w;
    }
    int e0 = row_ptr[node], e1 = row_ptr[node + 1];
    int e = e0;
    for (; e + 4 <= e1; e += 4) {
        int s0 = csr_src[e + 0], s1 = csr_src[e + 1];
        int s2 = csr_src[e + 2], s3 = csr_src[e + 3];
        float w0 = csr_norm[e + 0], w1 = csr_norm[e + 1];
        float w2 = csr_norm[e + 2], w3 = csr_norm[e + 3];
        if (act) {
            float4 h0 = ((const float4*)(h + (size_t)s0 * FV * 4))[lane];
            float4 h1 = ((const float4*)(h + (size_t)s1 * FV * 4))[lane];
            float4 h2 = ((const float4*)(h + (size_t)s2 * FV * 4))[lane];
            float4 h3 = ((const float4*)(h + (size_t)s3 * FV * 4))[lane];
            acc.x = fmaf(w0, h0.x, acc.x); acc.y = fmaf(w0, h0.y, acc.y);
            acc.z = fmaf(w0, h0.z, acc.z); acc.w = fmaf(w0, h0.w, acc.w);
            acc.x = fmaf(w1, h1.x, acc.x); acc.y = fmaf(w1, h1.y, acc.y);
            acc.z = fmaf(w1, h1.z, acc.z); acc.w = fmaf(w1, h1.w, acc.w);
            acc.x = fmaf(w2, h2.x, acc.x); acc.y = fmaf(w2, h2.y, acc.y);
            acc.z = fmaf(w2, h2.z, acc.z); acc.w = fmaf(w2, h2.w, acc.w);
            acc.x = fmaf(w3, h3.x, acc.x); acc.y = fmaf(w3, h3.y, acc.y);
            acc.z = fmaf(w3, h3.z, acc.z); acc.w = fmaf(w3, h3.w, acc.w);
        }
    }
    for (; e < e1; ++e) {
        int s = csr_src[e];
        float w = csr_norm[e];
        if (act) {
            float4 hv = ((const float4*)(h + (size_t)s * FV * 4))[lane];
            acc.x = fmaf(w, hv.x, acc.x);
            acc.y = fmaf(w, hv.y, acc.y);
            acc.z = fmaf(w, hv.z, acc.z);
            acc.w = fmaf(w, hv.w, acc.w);
        }
    }
    if (act) {
        float4 b = ((const float4*)bias)[lane];
        float4 r = make_float4(acc.x + b.x, acc.y + b.y, acc.z + b.z, acc.w + b.w);
        ((float4*)(out + (size_t)node * FV * 4))[lane] = r;
    }
}

// ---------------- GEMM: Y[r, ocol + c] = sum_k X[r,k] * W[k,c], K fixed 128 ----------------
template <int CG, int RPT>
__global__ __launch_bounds__(256) void gemm_kernel(const float* __restrict__ X,
                                                   const float* __restrict__ W,
                                                   float* __restrict__ Y, int nrows, int fout,
                                                   int ostride, int ocol) {
    __shared__ float Ws[32][CG * 4];
    __shared__ float Xs[64][32];
    int tid = threadIdx.x;
    int row0 = blockIdx.x * 64;
    int cg = tid % CG;
    int rg = tid / CG;
    float4 acc[RPT];
#pragma unroll
    for (int i = 0; i < RPT; ++i) acc[i] = make_float4(0.f, 0.f, 0.f, 0.f);
    for (int kc = 0; kc < 4; ++kc) {
        for (int i = tid; i < 32 * CG; i += 256) {
            int r = i / CG, c = i % CG;
            float4 w;
            if ((c * 4 + 3) < fout) {
                w = *(const float4*)(W + (size_t)(kc * 32 + r) * fout + c * 4);
            } else {
                float t0 = (c * 4 + 0) < fout ? W[(size_t)(kc * 32 + r) * fout + c * 4 + 0] : 0.f;
                float t1 = (c * 4 + 1) < fout ? W[(size_t)(kc * 32 + r) * fout + c * 4 + 1] : 0.f;
                float t2 = (c * 4 + 2) < fout ? W[(size_t)(kc * 32 + r) * fout + c * 4 + 2] : 0.f;
                float t3 = (c * 4 + 3) < fout ? W[(size_t)(kc * 32 + r) * fout + c * 4 + 3] : 0.f;
                w = make_float4(t0, t1, t2, t3);
            }
            *(float4*)&Ws[r][c * 4] = w;
        }
        for (int i = tid; i < 64 * 8; i += 256) {
            int r = i / 8, c = i % 8;
            int gr = row0 + r;
            float4 v = make_float4(0.f, 0.f, 0.f, 0.f);
            if (gr < nrows) v = *(const float4*)(X + (size_t)gr * DFEAT + kc * 32 + c * 4);
            *(float4*)&Xs[r][c * 4] = v;
        }
        __syncthreads();
#pragma unroll
        for (int k = 0; k < 32; ++k) {
            float4 w = *(float4*)&Ws[k][cg * 4];
#pragma unroll
            for (int i = 0; i < RPT; ++i) {
                float a = Xs[rg * RPT + i][k];
                acc[i].x = fmaf(a, w.x, acc[i].x);
                acc[i].y = fmaf(a, w.y, acc[i].y);
                acc[i].z = fmaf(a, w.z, acc[i].z);
                acc[i].w = fmaf(a, w.w, acc[i].w);
            }
        }
        __syncthreads();
    }
    if (cg * 4 < fout) {
#pragma unroll
        for (int i = 0; i < RPT; ++i) {
            int r = row0 + rg * RPT + i;
            if (r < nrows) *(float4*)(Y + (size_t)r * ostride + ocol + cg * 4) = acc[i];
        }
    }
}

// ---------------- BN statistics: per-column sum and sumsq (2-level) ----------------
__global__ __launch_bounds__(256) void stats2_kernel(const float* __restrict__ A,
                                                     const float* __restrict__ B,
                                                     float* __restrict__ stats, int nrows) {
    __shared__ float red1[256];
    __shared__ float red2[256];
    int t = threadIdx.x;
    int col = t & 127;
    int rg = t >> 7;  // 0 or 1
    const float* src = (blockIdx.y == 0) ? A : B;
    float* st = stats + (size_t)blockIdx.y * 256;
    int r0 = blockIdx.x * 128 + rg * 64;
    int r1 = min(r0 + 64, nrows);
    float s = 0.f, s2 = 0.f;
    for (int r = r0; r < r1; ++r) {
        float v = src[(size_t)r * DFEAT + col];
        s += v;
        s2 = fmaf(v, v, s2);
    }
    red1[t] = s;
    red2[t] = s2;
    __syncthreads();
    if (t < 128) {
        float fs = red1[t] + red1[t + 128];
        float fs2 = red2[t] + red2[t + 128];
        atomicAdd(&st[col], fs);
        atomicAdd(&st[DFEAT + col], fs2);
    }
}

// ---------------- BN scale/shift + sigmoid gates from row N-1 ----------------
__global__ __launch_bounds__(128) void gate_prep_kernel(
    const float* __restrict__ statsA, const float* __restrict__ statsB,
    const float* __restrict__ preA, const float* __restrict__ preB,
    const float* __restrict__ gamma, const float* __restrict__ beta,
    const float* __restrict__ gwA, const float* __restrict__ gbA,
    const float* __restrict__ gwB, const float* __restrict__ gbB,
    float* __restrict__ ss, float* __restrict__ wout, int nrows) {
    __shared__ float red[128];
    __shared__ float dotA_s;
    int t = threadIdx.x;
    float invN = 1.f / (float)nrows;
    float meanA = statsA[t] * invN;
    float varA = statsA[DFEAT + t] * invN - meanA * meanA;
    float scA = gamma[t] * rsqrtf(varA + 1e-5f);
    float shA = beta[t] - meanA * scA;
    ss[t] = scA;
    ss[DFEAT + t] = shA;
    float meanB = statsB[t] * invN;
    float varB = statsB[DFEAT + t] * invN - meanB * meanB;
    float scB = gamma[t] * rsqrtf(varB + 1e-5f);
    float shB = beta[t] - meanB * scB;
    ss[2 * DFEAT + t] = scB;
    ss[3 * DFEAT + t] = shB;
    float av = fmaxf(fmaf(preA[(size_t)(nrows - 1) * DFEAT + t], scA, shA), 0.f);
    red[t] = av * gwA[t];
    __syncthreads();
    for (int s = 64; s > 0; s >>= 1) {
        if (t < s) red[t] += red[t + s];
        __syncthreads();
    }
    if (t == 0) dotA_s = red[0];
    __syncthreads();
    float bv = fmaxf(fmaf(preB[(size_t)(nrows - 1) * DFEAT + t], scB, shB), 0.f);
    red[t] = bv * gwB[t];
    __syncthreads();
    for (int s = 64; s > 0; s >>= 1) {
        if (t < s) red[t] += red[t + s];
        __syncthreads();
    }
    if (t == 0) {
        float s1 = 1.f / (1.f + expf(-(dotA_s + gbA[0])));
        float s2 = 1.f / (1.f + expf(-(red[0] + gbB[0])));
        float tt = s1 + s2;
        wout[0] = s1 / tt;
        wout[1] = s2 / tt;
    }
}

// gates for the final layer (no BN), F = nclass
__global__ __launch_bounds__(64) void gate_final_kernel(
    const float* __restrict__ p1, const float* __restrict__ p2,
    const float* __restrict__ w1v, const float* __restrict__ b1,
    const float* __restrict__ w2v, const float* __restrict__ b2,
    float* __restrict__ wout, int nrows, int nclass) {
    __shared__ float red[64];
    __shared__ float dot1_s;
    int t = threadIdx.x;
    float v = (t < nclass) ? p1[(size_t)(nrows - 1) * nclass + t] * w1v[t] : 0.f;
    red[t] = v;
    __syncthreads();
    for (int s = 32; s > 0; s >>= 1) {
        if (t < s) red[t] += red[t + s];
        __syncthreads();
    }
    if (t == 0) dot1_s = red[0];
    __syncthreads();
    v = (t < nclass) ? p2[(size_t)(nrows - 1) * nclass + t] * w2v[t] : 0.f;
    red[t] = v;
    __syncthreads();
    for (int s = 32; s > 0; s >>= 1) {
        if (t < s) red[t] += red[t + s];
        __syncthreads();
    }
    if (t == 0) {
        float s1 = 1.f / (1.f + expf(-(dot1_s + b1[0])));
        float s2 = 1.f / (1.f + expf(-(red[0] + b2[0])));
        float tt = s1 + s2;
        wout[0] = s1 / tt;
        wout[1] = s2 / tt;
    }
}

// ---------------- combine: X = w1*relu(bn(A)) + w2*relu(bn(B)) ----------------
__global__ __launch_bounds__(256) void combine_kernel(const float* __restrict__ A,
                                                      const float* __restrict__ B,
                                                      const float* __restrict__ ss,
                                                      const float* __restrict__ wout,
                                                      float* __restrict__ X, int n4) {
    int idx = blockIdx.x * blockDim.x + threadIdx.x;
    if (idx >= n4) return;
    int c = (idx & 31) * 4;
    float4 a = *(const float4*)(A + (size_t)idx * 4);
    float4 b = *(const float4*)(B + (size_t)idx * 4);
    float4 scA = *(const float4*)(ss + c);
    float4 shA = *(const float4*)(ss + DFEAT + c);
    float4 scB = *(const float4*)(ss + 2 * DFEAT + c);
    float4 shB = *(const float4*)(ss + 3 * DFEAT + c);
    float w1 = wout[0], w2 = wout[1];
    float4 r;
    r.x = w1 * fmaxf(fmaf(a.x, scA.x, shA.x), 0.f) + w2 * fmaxf(fmaf(b.x, scB.x, shB.x), 0.f);
    r.y = w1 * fmaxf(fmaf(a.y, scA.y, shA.y), 0.f) + w2 * fmaxf(fmaf(b.y, scB.y, shB.y), 0.f);
    r.z = w1 * fmaxf(fmaf(a.z, scA.z, shA.z), 0.f) + w2 * fmaxf(fmaf(b.z, scB.z, shB.z), 0.f);
    r.w = w1 * fmaxf(fmaf(a.w, scA.w, shA.w), 0.f) + w2 * fmaxf(fmaf(b.w, scB.w, shB.w), 0.f);
    *(float4*)(X + (size_t)idx * 4) = r;
}

__global__ __launch_bounds__(256) void mix_kernel(const float* __restrict__ p1,
                                                  const float* __restrict__ p2,
                                                  const float* __restrict__ wout,
                                                  float* __restrict__ o, int n4) {
    int idx = blockIdx.x * blockDim.x + threadIdx.x;
    if (idx >= n4) return;
    float w1 = wout[0], w2 = wout[1];
    float4 a = *(const float4*)(p1 + (size_t)idx * 4);
    float4 b = *(const float4*)(p2 + (size_t)idx * 4);
    float4 r = make_float4(w1 * a.x + w2 * b.x, w1 * a.y + w2 * b.y, w1 * a.z + w2 * b.z,
                           w1 * a.w + w2 * b.w);
    *(float4*)(o + (size_t)idx * 4) = r;
}

extern "C" void kernel_launch(void* const* d_in, const int* in_sizes, int n_in, void* d_out,
                              int out_size, void* d_ws, size_t ws_size, hipStream_t stream) {
    (void)n_in; (void)out_size; (void)ws_size;
    const int N = in_sizes[0] / DFEAT;        // 50000
    const int E = in_sizes[4] / 2;            // 800000
    const int NC = in_sizes[15];              // 40

    const float* x1a = (const float*)d_in[0];
    const float* x1b = (const float*)d_in[1];
    const float* x2a = (const float*)d_in[2];
    const float* x2b = (const float*)d_in[3];
    const int* ei1 = (const int*)d_in[4];
    const int* ei2 = (const int*)d_in[5];
    const float* Wi = (const float*)d_in[6];      // (2,128,64)
    const float* bi = (const float*)d_in[7];      // (2,64) flat = concat bias
    const float* gi = (const float*)d_in[8];
    const float* bei = (const float*)d_in[9];
    const float* Wm = (const float*)d_in[10];     // (2,128,128)
    const float* bm = (const float*)d_in[11];
    const float* gm = (const float*)d_in[12];
    const float* bem = (const float*)d_in[13];
    const float* Wf = (const float*)d_in[14];     // (128,40)
    const float* bf = (const float*)d_in[15];
    const float* fc1w1_W = (const float*)d_in[16];
    const float* fc1w1_b = (const float*)d_in[17];
    const float* fc1w2_W = (const float*)d_in[18];
    const float* fc1w2_b = (const float*)d_in[19];
    const float* aws_w1_W = (const float*)d_in[20];
    const float* aws_w1_b = (const float*)d_in[21];
    const float* aws_w2_W = (const float*)d_in[22];
    const float* aws_w2_b = (const float*)d_in[23];
    const float* fcw1_W = (const float*)d_in[24];
    const float* fcw1_b = (const float*)d_in[25];
    const float* fcw2_W = (const float*)d_in[26];
    const float* fcw2_b = (const float*)d_in[27];

    char* ws = (char*)d_ws;
    size_t off = 0;
    auto alloc = [&](size_t bytes) -> char* {
        char* p = ws + off;
        off += (bytes + 255) & ~(size_t)255;
        return p;
    };
    float* P = (float*)alloc((size_t)N * DFEAT * 4);
    float* Q = (float*)alloc((size_t)N * DFEAT * 4);
    float* R = (float*)alloc((size_t)N * DFEAT * 4);
    int* rp1 = (int*)alloc((size_t)(N + 1) * 4);
    int* cnt1 = (int*)alloc((size_t)N * 4);
    int* fl1 = (int*)alloc((size_t)N * 4);
    float* dv1 = (float*)alloc((size_t)N * 4);
    int* cs1 = (int*)alloc((size_t)E * 4);
    float* cn1 = (float*)alloc((size_t)E * 4);
    int* rp2 = (int*)alloc((size_t)(N + 1) * 4);
    int* cnt2 = (int*)alloc((size_t)N * 4);
    int* fl2 = (int*)alloc((size_t)N * 4);
    float* dv2 = (float*)alloc((size_t)N * 4);
    int* cs2 = (int*)alloc((size_t)E * 4);
    float* cn2 = (float*)alloc((size_t)E * 4);
    float* stats = (float*)alloc(2048);  // statsA (256) + statsB (256)
    float* statsA = stats;
    float* statsB = stats + 256;
    float* ssbuf = (float*)alloc(2048);  // scaleA, shiftA, scaleB, shiftB
    float* wout = (float*)alloc(256);
    int nb = (N + 2047) / 2048;  // 25
    int* bsums = (int*)alloc((size_t)2 * nb * 4);

    const int* src1 = ei1;
    const int* dst1 = ei1 + E;
    const int* src2 = ei2;
    const int* dst2 = ei2 + E;

    int ebl = (E + 255) / 256;
    int gemmbl = (N + 63) / 64;
    int aggbl128 = (N * 32 + 255) / 256;
    int aggbl40 = (N * 16 + 255) / 256;
    int combbl = (N * 32 + 255) / 256;
    dim3 statgrid((N + 127) / 128, 2);
    dim3 scangrid(nb, 2);

    // ---- CSR build ----
    hipMemsetAsync(cnt1, 0, (size_t)N * 4, stream);
    hipMemsetAsync(fl1, 0, (size_t)N * 4, stream);
    hipMemsetAsync(cnt2, 0, (size_t)N * 4, stream);
    hipMemsetAsync(fl2, 0, (size_t)N * 4, stream);
    count_kernel<<<ebl, 256, 0, stream>>>(dst1, cnt1, E);
    count_kernel<<<ebl, 256, 0, stream>>>(dst2, cnt2, E);
    blocksum_kernel<<<scangrid, 256, 0, stream>>>(cnt1, cnt2, bsums, N, nb);
    scansums_kernel<<<1, 64, 0, stream>>>(bsums, nb, rp1, rp2, N, E);
    writerp_kernel<<<scangrid, 256, 0, stream>>>(cnt1, cnt2, bsums, rp1, rp2, dv1, dv2, N, nb);
    fill_kernel<<<ebl, 256, 0, stream>>>(src1, dst1, rp1, fl1, cs1, cn1, dv1, E);
    fill_kernel<<<ebl, 256, 0, stream>>>(src2, dst2, rp2, fl2, cs2, cn2, dv2, E);

    // ---- Layer 1: h = concat halves ----
    gemm_kernel<16, 4><<<gemmbl, 256, 0, stream>>>(x1a, Wi, P, N, 64, DFEAT, 0);
    gemm_kernel<16, 4><<<gemmbl, 256, 0, stream>>>(x1b, Wi + 128 * 64, P, N, 64, DFEAT, 64);
    gemm_kernel<16, 4><<<gemmbl, 256, 0, stream>>>(x2a, Wi, Q, N, 64, DFEAT, 0);
    gemm_kernel<16, 4><<<gemmbl, 256, 0, stream>>>(x2b, Wi + 128 * 64, Q, N, 64, DFEAT, 64);
    agg_kernel<32, 32><<<aggbl128, 256, 0, stream>>>(P, rp1, cs1, cn1, dv1, bi, R, N);  // pre1 -> R
    agg_kernel<32, 32><<<aggbl128, 256, 0, stream>>>(Q, rp2, cs2, cn2, dv2, bi, P, N);  // pre2 -> P
    hipMemsetAsync(stats, 0, 2048, stream);
    stats2_kernel<<<statgrid, 256, 0, stream>>>(R, P, stats, N);
    gate_prep_kernel<<<1, 128, 0, stream>>>(statsA, statsB, R, P, gi, bei, fc1w1_W, fc1w1_b,
                                            fc1w2_W, fc1w2_b, ssbuf, wout, N);
    combine_kernel<<<combbl, 256, 0, stream>>>(R, P, ssbuf, wout, Q, N * 32);  // X -> Q

    // ---- Middle layers ----
    // i=0: X in Q
    gemm_kernel<32, 8><<<gemmbl, 256, 0, stream>>>(Q, Wm, P, N, 128, 128, 0);
    agg_kernel<32, 32><<<aggbl128, 256, 0, stream>>>(P, rp1, cs1, cn1, dv1, bm, Q, N);
    agg_kernel<32, 32><<<aggbl128, 256, 0, stream>>>(P, rp2, cs2, cn2, dv2, bm, R, N);
    hipMemsetAsync(stats, 0, 2048, stream);
    stats2_kernel<<<statgrid, 256, 0, stream>>>(Q, R, stats, N);
    gate_prep_kernel<<<1, 128, 0, stream>>>(statsA, statsB, Q, R, gm, bem, aws_w1_W, aws_w1_b,
                                            aws_w2_W, aws_w2_b, ssbuf, wout, N);
    combine_kernel<<<combbl, 256, 0, stream>>>(Q, R, ssbuf, wout, P, N * 32);  // X -> P

    // i=1: X in P
    gemm_kernel<32, 8><<<gemmbl, 256, 0, stream>>>(P, Wm + 128 * 128, Q, N, 128, 128, 0);
    agg_kernel<32, 32><<<aggbl128, 256, 0, stream>>>(Q, rp1, cs1, cn1, dv1, bm + 128, P, N);
    agg_kernel<32, 32><<<aggbl128, 256, 0, stream>>>(Q, rp2, cs2, cn2, dv2, bm + 128, R, N);
    hipMemsetAsync(stats, 0, 2048, stream);
    stats2_kernel<<<statgrid, 256, 0, stream>>>(P, R, stats, N);
    gate_prep_kernel<<<1, 128, 0, stream>>>(statsA, statsB, P, R, gm + 128, bem + 128,
                                            aws_w1_W + 128, aws_w1_b + 1, aws_w2_W + 128,
                                            aws_w2_b + 1, ssbuf, wout, N);
    combine_kernel<<<combbl, 256, 0, stream>>>(P, R, ssbuf, wout, Q, N * 32);  // X -> Q

    // ---- Final layer ----
    float* out0 = (float*)d_out;
    float* p1 = out0 + (size_t)N * NC;
    float* p2 = out0 + (size_t)2 * N * NC;
    gemm_kernel<16, 4><<<gemmbl, 256, 0, stream>>>(Q, Wf, P, N, NC, NC, 0);  // HF -> P (N x 40)
    agg_kernel<10, 16><<<aggbl40, 256, 0, stream>>>(P, rp1, cs1, cn1, dv1, bf, p1, N);
    agg_kernel<10, 16><<<aggbl40, 256, 0, stream>>>(P, rp2, cs2, cn2, dv2, bf, p2, N);
    gate_final_kernel<<<1, 64, 0, stream>>>(p1, p2, fcw1_W, fcw1_b, fcw2_W, fcw2_b, wout, N, NC);
    mix_kernel<<<(N * NC / 4 + 255) / 256, 256, 0, stream>>>(p1, p2, wout, out0, N * NC / 4);
}